// Round 1
// 1185.698 us; speedup vs baseline: 1.0530x; 1.0530x over previous
//
#include <hip/hip_runtime.h>
#include <stdint.h>

// Problem constants: E=8, T=1024, D_IN=2048, D_OUT=8192
#define E_   8
#define T_   1024
#define DI_  2048
#define DO_  8192

#define BM   128
#define BN   128
#define BK   64

typedef __attribute__((ext_vector_type(8))) short bf16x8;   // 8 bf16 = 4 VGPRs (MFMA A/B frag)
typedef __attribute__((ext_vector_type(4))) float f32x4;    // MFMA C/D frag

// Pack two fp32 bit patterns into two bf16 (truncate; exact for int-valued inputs |v|<=127).
__device__ __forceinline__ uint32_t pack_bf16(uint32_t lo, uint32_t hi) {
    return (hi & 0xFFFF0000u) | (lo >> 16);
}

// Round-to-nearest-even fp32 -> bf16 pair (for the activation conversion).
__device__ __forceinline__ uint32_t pack_bf16_rne(float a, float b) {
    uint32_t ua = __float_as_uint(a), ub = __float_as_uint(b);
    uint32_t ra = (ua + 0x7FFFu + ((ua >> 16) & 1u)) >> 16;
    uint32_t rb = (ub + 0x7FFFu + ((ub >> 16) & 1u)) >> 16;
    return ra | (rb << 16);
}

// ---------------------------------------------------------------------------
// Pre-pass 1: weights int32 -> bf16 (exact: |w| <= 127 fits bf16's 8-bit mantissa)
// ---------------------------------------------------------------------------
__global__ __launch_bounds__(256)
void cvt_w_kernel(const int* __restrict__ src, ushort* __restrict__ dst) {
    const size_t n8 = (size_t)E_ * DO_ * DI_ / 8;           // 16.7M chunks of 8
    const size_t stride = (size_t)gridDim.x * 256;
    for (size_t i = (size_t)blockIdx.x * 256 + threadIdx.x; i < n8; i += stride) {
        const int4* p = (const int4*)(src + i * 8);
        int4 v0 = p[0], v1 = p[1];
        uint4 o;
        o.x = pack_bf16(__float_as_uint((float)v0.x), __float_as_uint((float)v0.y));
        o.y = pack_bf16(__float_as_uint((float)v0.z), __float_as_uint((float)v0.w));
        o.z = pack_bf16(__float_as_uint((float)v1.x), __float_as_uint((float)v1.y));
        o.w = pack_bf16(__float_as_uint((float)v1.z), __float_as_uint((float)v1.w));
        *(uint4*)(dst + i * 8) = o;                          // 16 B store
    }
}

// ---------------------------------------------------------------------------
// Pre-pass 2: activations fp32 -> bf16 (RNE)
// ---------------------------------------------------------------------------
__global__ __launch_bounds__(256)
void cvt_a_kernel(const float* __restrict__ src, ushort* __restrict__ dst) {
    const size_t n8 = (size_t)E_ * T_ * DI_ / 8;            // 2.1M chunks of 8
    const size_t stride = (size_t)gridDim.x * 256;
    for (size_t i = (size_t)blockIdx.x * 256 + threadIdx.x; i < n8; i += stride) {
        const float4* p = (const float4*)(src + i * 8);
        float4 f0 = p[0], f1 = p[1];
        uint4 o;
        o.x = pack_bf16_rne(f0.x, f0.y);
        o.y = pack_bf16_rne(f0.z, f0.w);
        o.z = pack_bf16_rne(f1.x, f1.y);
        o.w = pack_bf16_rne(f1.z, f1.w);
        *(uint4*)(dst + i * 8) = o;
    }
}

// ---------------------------------------------------------------------------
// Main GEMM: bf16 x bf16 (both K-major), m97 structure:
// 128x128 tile, BK=64, linear LDS, global_load_lds width=16, 2 barriers/K-step.
// ---------------------------------------------------------------------------
__device__ __forceinline__ void gload_lds16(const void* g, void* lds) {
    // LDS dest is wave-uniform base; HW scatters lane i at base + i*16 (m104/m108).
    __builtin_amdgcn_global_load_lds(
        (const __attribute__((address_space(1))) void*)g,
        (__attribute__((address_space(3))) void*)lds,
        16, 0, 0);
}

__global__ __launch_bounds__(256)
void qgemm_lds_kernel(const ushort* __restrict__ A,    // [E, T, DI] bf16
                      const ushort* __restrict__ W,    // [E, DO, DI] bf16
                      const float*  __restrict__ scale,
                      float*        __restrict__ out) {
    // Linear LDS (REQUIRED for global_load_lds: dest = base + lane*16, no padding).
    __shared__ __align__(16) ushort As[BM * BK];   // 16 KiB
    __shared__ __align__(16) ushort Bs[BN * BK];   // 16 KiB

    const int tid  = threadIdx.x;
    const int e    = blockIdx.y;
    // m-fastest within expert: 8 consecutive blocks share the B (weight) slab -> L2/L3 reuse.
    const int m0 = (blockIdx.x & 7) * BM;
    const int n0 = (blockIdx.x >> 3) * BN;

    const int lane = tid & 63;
    const int wave = tid >> 6;

    // Staging geometry: issue i covers tile rows [i*32, i*32+32); within an issue,
    // wave w + lane covers row w*8 + lane/8, cols (lane&7)*8 .. +8  (16 B contiguous).
    const int srow = wave * 8 + (lane >> 3);      // 0..31
    const int scol = (lane & 7) * 8;              // 0,8,...,56

    const ushort* Ag = A + ((size_t)(e * T_  + m0 + srow)) * DI_ + scol;
    const ushort* Bg = W + ((size_t)(e * DO_ + n0 + srow)) * DI_ + scol;
    ushort* AsW = &As[wave * 512];                // wave-uniform LDS base (1 KiB per wave)
    ushort* BsW = &Bs[wave * 512];

    // MFMA geometry: 2x2 wave grid, each wave owns a 64x64 output subtile.
    const int wm = (wave >> 1) * 64;
    const int wn = (wave & 1) * 64;
    const int fr = lane & 15;                     // fragment row (A) / col (B)
    const int fq = lane >> 4;                     // quad: k-offset fq*8

    f32x4 acc[4][4];
    #pragma unroll
    for (int i = 0; i < 4; i++)
        #pragma unroll
        for (int j = 0; j < 4; j++)
            acc[i][j] = (f32x4){0.f, 0.f, 0.f, 0.f};

    const int KT = DI_ / BK;  // 32 K-tiles
    for (int kt = 0; kt < KT; kt++) {
        const ushort* Ak = Ag + kt * BK;
        const ushort* Bk = Bg + kt * BK;
        // 4 issues per matrix: each issue stages 32 rows x 64 cols (4 KiB).
        #pragma unroll
        for (int i = 0; i < 4; i++) {
            gload_lds16(Ak + (size_t)i * 32 * DI_, AsW + i * 2048);
            gload_lds16(Bk + (size_t)i * 32 * DI_, BsW + i * 2048);
        }
        __syncthreads();   // compiler emits s_waitcnt vmcnt(0) lgkmcnt(0) before s_barrier

        #pragma unroll
        for (int ks = 0; ks < 2; ks++) {
            bf16x8 af[4], bfv[4];
            #pragma unroll
            for (int i = 0; i < 4; i++) {
                af[i]  = *(const bf16x8*)&As[(wm + i * 16 + fr) * BK + ks * 32 + fq * 8];
                bfv[i] = *(const bf16x8*)&Bs[(wn + i * 16 + fr) * BK + ks * 32 + fq * 8];
            }
            #pragma unroll
            for (int i = 0; i < 4; i++)
                #pragma unroll
                for (int j = 0; j < 4; j++)
                    acc[i][j] = __builtin_amdgcn_mfma_f32_16x16x32_bf16(
                        af[i], bfv[j], acc[i][j], 0, 0, 0);
        }
        __syncthreads();
    }

    // Epilogue: C/D layout col=lane&15, row=(lane>>4)*4+reg. Apply per-expert scale.
    const float s = scale[e];
    float* Cbase = out + ((size_t)e * T_ + m0) * DO_ + n0;
    #pragma unroll
    for (int i = 0; i < 4; i++) {
        #pragma unroll
        for (int j = 0; j < 4; j++) {
            #pragma unroll
            for (int r = 0; r < 4; r++) {
                const int row = wm + i * 16 + fq * 4 + r;
                const int col = wn + j * 16 + fr;
                Cbase[(size_t)row * DO_ + col] = acc[i][j][r] * s;
            }
        }
    }
}

// ---------------------------------------------------------------------------
// Fallback: previous fused kernel (used only if workspace is too small).
// ---------------------------------------------------------------------------
#define PAD  8
#define LDST (BK + PAD)

__global__ __launch_bounds__(256, 2)
void qgemm_bf16_kernel(const float* __restrict__ input,
                       const int*   __restrict__ weight,
                       const float* __restrict__ scale,
                       float*       __restrict__ out) {
    __shared__ ushort As[BM * LDST];
    __shared__ ushort Bs[BN * LDST];

    const int tid = threadIdx.x;
    const int e   = blockIdx.y;
    const int m0 = (blockIdx.x & 7) * BM;
    const int n0 = (blockIdx.x >> 3) * BN;

    const float* Abase = input  + ((size_t)e * T_  + m0) * DI_;
    const int*   Bbase = weight + ((size_t)e * DO_ + n0) * DI_;

    const int srow = tid >> 3;
    const int scol = (tid & 7) * 8;

    const int lane = tid & 63;
    const int wave = tid >> 6;
    const int wm = (wave >> 1) * 64;
    const int wn = (wave & 1) * 64;
    const int fr = lane & 15;
    const int fq = lane >> 4;

    f32x4 acc[4][4];
    #pragma unroll
    for (int i = 0; i < 4; i++)
        #pragma unroll
        for (int j = 0; j < 4; j++)
            acc[i][j] = (f32x4){0.f, 0.f, 0.f, 0.f};

    float4 aRegs[4][2];
    int4   bRegs[4][2];

    #pragma unroll
    for (int p = 0; p < 4; p++) {
        const float* ap = Abase + (size_t)(srow + p * 32) * DI_ + scol;
        aRegs[p][0] = *(const float4*)ap;
        aRegs[p][1] = *(const float4*)(ap + 4);
        const int* bp = Bbase + (size_t)(srow + p * 32) * DI_ + scol;
        bRegs[p][0] = *(const int4*)bp;
        bRegs[p][1] = *(const int4*)(bp + 4);
    }

    const int KT = DI_ / BK;
    for (int kt = 0; kt < KT; kt++) {
        #pragma unroll
        for (int p = 0; p < 4; p++) {
            float4 f0 = aRegs[p][0], f1 = aRegs[p][1];
            uint4 w;
            w.x = pack_bf16(__float_as_uint(f0.x), __float_as_uint(f0.y));
            w.y = pack_bf16(__float_as_uint(f0.z), __float_as_uint(f0.w));
            w.z = pack_bf16(__float_as_uint(f1.x), __float_as_uint(f1.y));
            w.w = pack_bf16(__float_as_uint(f1.z), __float_as_uint(f1.w));
            *(uint4*)&As[(srow + p * 32) * LDST + scol] = w;

            int4 i0 = bRegs[p][0], i1 = bRegs[p][1];
            uint4 v;
            v.x = pack_bf16(__float_as_uint((float)i0.x), __float_as_uint((float)i0.y));
            v.y = pack_bf16(__float_as_uint((float)i0.z), __float_as_uint((float)i0.w));
            v.z = pack_bf16(__float_as_uint((float)i1.x), __float_as_uint((float)i1.y));
            v.w = pack_bf16(__float_as_uint((float)i1.z), __float_as_uint((float)i1.w));
            *(uint4*)&Bs[(srow + p * 32) * LDST + scol] = v;
        }
        __syncthreads();

        if (kt + 1 < KT) {
            const float* An = Abase + (size_t)(kt + 1) * BK;
            const int*   Bn = Bbase + (size_t)(kt + 1) * BK;
            #pragma unroll
            for (int p = 0; p < 4; p++) {
                const float* ap = An + (size_t)(srow + p * 32) * DI_ + scol;
                aRegs[p][0] = *(const float4*)ap;
                aRegs[p][1] = *(const float4*)(ap + 4);
                const int* bp = Bn + (size_t)(srow + p * 32) * DI_ + scol;
                bRegs[p][0] = *(const int4*)bp;
                bRegs[p][1] = *(const int4*)(bp + 4);
            }
        }

        #pragma unroll
        for (int ks = 0; ks < 2; ks++) {
            bf16x8 afrag[4], bfrag[4];
            #pragma unroll
            for (int i = 0; i < 4; i++) {
                afrag[i] = *(const bf16x8*)&As[(wm + i * 16 + fr) * LDST + ks * 32 + fq * 8];
                bfrag[i] = *(const bf16x8*)&Bs[(wn + i * 16 + fr) * LDST + ks * 32 + fq * 8];
            }
            #pragma unroll
            for (int i = 0; i < 4; i++)
                #pragma unroll
                for (int j = 0; j < 4; j++)
                    acc[i][j] = __builtin_amdgcn_mfma_f32_16x16x32_bf16(
                        afrag[i], bfrag[j], acc[i][j], 0, 0, 0);
        }
        __syncthreads();
    }

    const float s = scale[e];
    float* Cbase = out + ((size_t)e * T_ + m0) * DO_ + n0;
    #pragma unroll
    for (int i = 0; i < 4; i++) {
        #pragma unroll
        for (int j = 0; j < 4; j++) {
            #pragma unroll
            for (int r = 0; r < 4; r++) {
                const int row = wm + i * 16 + fq * 4 + r;
                const int col = wn + j * 16 + fr;
                Cbase[(size_t)row * DO_ + col] = acc[i][j][r] * s;
            }
        }
    }
}

// ---------------------------------------------------------------------------
extern "C" void kernel_launch(void* const* d_in, const int* in_sizes, int n_in,
                              void* d_out, int out_size, void* d_ws, size_t ws_size,
                              hipStream_t stream) {
    const float* input  = (const float*)d_in[0];
    const int*   weight = (const int*)d_in[1];
    const float* scale  = (const float*)d_in[2];
    float* out = (float*)d_out;

    const size_t wbytes = (size_t)E_ * DO_ * DI_ * sizeof(ushort);  // 256 MiB
    const size_t abytes = (size_t)E_ * T_  * DI_ * sizeof(ushort);  //  32 MiB

    dim3 grid((T_ / BM) * (DO_ / BN), E_, 1);  // 512 tiles x 8 experts = 4096 blocks
    dim3 block(256, 1, 1);

    if (d_ws != nullptr && ws_size >= wbytes + abytes) {
        ushort* Wbf = (ushort*)d_ws;
        ushort* Abf = (ushort*)((char*)d_ws + wbytes);
        cvt_w_kernel<<<dim3(2048), block, 0, stream>>>(weight, Wbf);
        cvt_a_kernel<<<dim3(1024), block, 0, stream>>>(input, Abf);
        qgemm_lds_kernel<<<grid, block, 0, stream>>>(Abf, Wbf, scale, out);
    } else {
        qgemm_bf16_kernel<<<grid, block, 0, stream>>>(input, weight, scale, out);
    }
}

// Round 2
// 1106.654 us; speedup vs baseline: 1.1282x; 1.0714x over previous
//
#include <hip/hip_runtime.h>
#include <stdint.h>

// Problem constants: E=8, T=1024, D_IN=2048, D_OUT=8192
#define E_   8
#define T_   1024
#define DI_  2048
#define DO_  8192

// ---- 256x256 K-slice-ring GEMM geometry ----
#define BM   256
#define BN   256
#define BKS  32                      // K-slice
#define NS   (DI_ / BKS)             // 64 slices
#define SLOT_U ((BM + BN) * BKS)     // 16384 ushorts = 32 KiB per ring slot
#define B_OFF  (BM * BKS)            // B region offset within slot (ushorts)

typedef __attribute__((ext_vector_type(8))) short bf16x8;   // 8 bf16 (MFMA A/B frag)
typedef __attribute__((ext_vector_type(4))) float f32x4;    // MFMA C/D frag

// Pack two fp32 bit patterns into two bf16 (truncate; exact for int-valued inputs |v|<=127).
__device__ __forceinline__ uint32_t pack_bf16(uint32_t lo, uint32_t hi) {
    return (hi & 0xFFFF0000u) | (lo >> 16);
}

// Round-to-nearest-even fp32 -> bf16 pair (for the activation conversion).
__device__ __forceinline__ uint32_t pack_bf16_rne(float a, float b) {
    uint32_t ua = __float_as_uint(a), ub = __float_as_uint(b);
    uint32_t ra = (ua + 0x7FFFu + ((ua >> 16) & 1u)) >> 16;
    uint32_t rb = (ub + 0x7FFFu + ((ub >> 16) & 1u)) >> 16;
    return ra | (rb << 16);
}

// ---------------------------------------------------------------------------
// Pre-pass 1: weights int32 -> bf16 (exact: |w| <= 127 fits bf16's 8-bit mantissa)
// ---------------------------------------------------------------------------
__global__ __launch_bounds__(256)
void cvt_w_kernel(const int* __restrict__ src, ushort* __restrict__ dst) {
    const size_t n8 = (size_t)E_ * DO_ * DI_ / 8;
    const size_t stride = (size_t)gridDim.x * 256;
    for (size_t i = (size_t)blockIdx.x * 256 + threadIdx.x; i < n8; i += stride) {
        const int4* p = (const int4*)(src + i * 8);
        int4 v0 = p[0], v1 = p[1];
        uint4 o;
        o.x = pack_bf16(__float_as_uint((float)v0.x), __float_as_uint((float)v0.y));
        o.y = pack_bf16(__float_as_uint((float)v0.z), __float_as_uint((float)v0.w));
        o.z = pack_bf16(__float_as_uint((float)v1.x), __float_as_uint((float)v1.y));
        o.w = pack_bf16(__float_as_uint((float)v1.z), __float_as_uint((float)v1.w));
        *(uint4*)(dst + i * 8) = o;
    }
}

// ---------------------------------------------------------------------------
// Pre-pass 2: activations fp32 -> bf16 (RNE)
// ---------------------------------------------------------------------------
__global__ __launch_bounds__(256)
void cvt_a_kernel(const float* __restrict__ src, ushort* __restrict__ dst) {
    const size_t n8 = (size_t)E_ * T_ * DI_ / 8;
    const size_t stride = (size_t)gridDim.x * 256;
    for (size_t i = (size_t)blockIdx.x * 256 + threadIdx.x; i < n8; i += stride) {
        const float4* p = (const float4*)(src + i * 8);
        float4 f0 = p[0], f1 = p[1];
        uint4 o;
        o.x = pack_bf16_rne(f0.x, f0.y);
        o.y = pack_bf16_rne(f0.z, f0.w);
        o.z = pack_bf16_rne(f1.x, f1.y);
        o.w = pack_bf16_rne(f1.z, f1.w);
        *(uint4*)(dst + i * 8) = o;
    }
}

// ---------------------------------------------------------------------------
// Main GEMM: 256x256 tile, 8 waves (2Mx4N), K-slice ring pipeline.
//   - ring of 4 slices (A[256x32]+B[256x32] bf16 each, 32 KiB) = 128 KiB LDS
//   - staging runs 3 slices ahead; counted s_waitcnt vmcnt(8) keeps 8
//     global_load_lds in flight ACROSS every barrier (T3+T4)
//   - T2: linear LDS dest + inverse-swizzled global source + swizzled read
//     (colblock16 ^= row&3) kills the 16-way bank conflict
//   - T5: setprio(1) around the MFMA cluster
// Correctness ledger (wave-independent, slice-granular):
//   phase s reads slot s&3 (landed: end-of-phase s-1 waits vmcnt(8) => slice
//   s+1's 4 oldest issues done, all waves, then barrier). Phase s stages slice
//   s+3 into slot (s-1)&3, whose readers all passed the end-of-phase s-1
//   barrier. Writes for slice s+3 land before phase s+3 reads them (end-of-
//   phase s+2 wait confirms slice s+3). Tail: vmcnt 8 -> 4 -> 0.
// ---------------------------------------------------------------------------
__device__ __forceinline__ void gload_lds16(const void* g, void* lds) {
    __builtin_amdgcn_global_load_lds(
        (const __attribute__((address_space(1))) void*)g,
        (__attribute__((address_space(3))) void*)lds,
        16, 0, 0);
}

__global__ __launch_bounds__(512, 2)
void qgemm_ring_kernel(const ushort* __restrict__ A,    // [E, T, DI] bf16
                       const ushort* __restrict__ W,    // [E, DO, DI] bf16
                       const float*  __restrict__ scale,
                       float*        __restrict__ out) {
    __shared__ __align__(16) ushort ring[4 * SLOT_U];   // 128 KiB

    const int tid  = threadIdx.x;
    const int lane = tid & 63;
    const int wave = tid >> 6;

    // T1: bijective XCD swizzle (1024 blocks % 8 == 0). Each XCD owns one
    // expert: A-expert (4 MiB) stays L2-resident, W streams once.
    const int flat = blockIdx.x;                 // 0..1023
    const int swz  = (flat & 7) * 128 + (flat >> 3);
    const int e    = swz >> 7;                   // expert
    const int t    = swz & 127;                  // tile within expert
    const int m0   = (t & 3) * BM;               // m-fastest: 4 m-blocks share B slab
    const int n0   = (t >> 2) * BN;

    const ushort* Ae = A + (size_t)e * T_  * DI_;
    const ushort* We = W + (size_t)e * DO_ * DI_;

    // Staging geometry: one issue = 128 rows x 64 B (8 KiB), thread t covers
    // (row = t>>2, colblock16 = t&3). LDS dest linear (byte = tid*16);
    // source column pre-swizzled: cb_src = (t&3) ^ (row&3)  (involution).
    const int srow = tid >> 2;                               // 0..127
    const int scol = (((tid & 3) ^ (srow & 3)) * 8);         // swizzled src col (elems)
    const ushort* Asrc0 = Ae + (size_t)(m0 + srow) * DI_ + scol;
    const ushort* Asrc1 = Asrc0 + (size_t)128 * DI_;
    const ushort* Bsrc0 = We + (size_t)(n0 + srow) * DI_ + scol;
    const ushort* Bsrc1 = Bsrc0 + (size_t)128 * DI_;
    const int ldsA0 = wave * 512;            // wave-uniform LDS bases (ushorts)
    const int ldsA1 = ldsA0 + 4096;
    const int ldsB0 = B_OFF + ldsA0;
    const int ldsB1 = B_OFF + ldsA1;

    #define STAGE(sl) do {                                       \
        ushort* _rb = &ring[((sl) & 3) * SLOT_U];                \
        const size_t _k = (size_t)(sl) * BKS;                    \
        gload_lds16(Asrc0 + _k, _rb + ldsA0);                    \
        gload_lds16(Asrc1 + _k, _rb + ldsA1);                    \
        gload_lds16(Bsrc0 + _k, _rb + ldsB0);                    \
        gload_lds16(Bsrc1 + _k, _rb + ldsB1);                    \
    } while (0)

    // MFMA geometry: wave (wr,wc) owns output rows [wr*128,+128) x cols [wc*64,+64).
    const int wr = wave >> 2;                    // 0..1
    const int wc = wave & 3;                     // 0..3
    const int fr = lane & 15;
    const int fq = lane >> 4;
    // Swizzled frag read: ushort off = row*32 + ((fq ^ (row&3))*8); row&3 == fr&3.
    const int xterm = (fq ^ (fr & 3)) * 8;
    const int offA0 = (wr * 128 + fr) * 32 + xterm;           // + i*512
    const int offB0 = B_OFF + (wc * 64 + fr) * 32 + xterm;    // + j*512

    f32x4 acc[8][4];
    #pragma unroll
    for (int i = 0; i < 8; i++)
        #pragma unroll
        for (int j = 0; j < 4; j++)
            acc[i][j] = (f32x4){0.f, 0.f, 0.f, 0.f};

    // Prologue: stage slices 0,1,2; wait slice 0 (8 issues stay in flight).
    STAGE(0); STAGE(1); STAGE(2);
    asm volatile("s_waitcnt vmcnt(8)" ::: "memory");
    __builtin_amdgcn_sched_barrier(0);
    __builtin_amdgcn_s_barrier();

    for (int s = 0; s < NS; ++s) {
        if (s + 3 < NS) STAGE(s + 3);
        __builtin_amdgcn_sched_barrier(0);       // pin load issue early in phase

        const ushort* sb = &ring[(s & 3) * SLOT_U];
        bf16x8 af[8], bf[4];
        #pragma unroll
        for (int j = 0; j < 4; ++j)
            bf[j] = *(const bf16x8*)&sb[offB0 + j * 512];
        #pragma unroll
        for (int i = 0; i < 8; ++i)
            af[i] = *(const bf16x8*)&sb[offA0 + i * 512];

        __builtin_amdgcn_s_setprio(1);
        #pragma unroll
        for (int i = 0; i < 8; ++i)
            #pragma unroll
            for (int j = 0; j < 4; ++j)
                acc[i][j] = __builtin_amdgcn_mfma_f32_16x16x32_bf16(
                    af[i], bf[j], acc[i][j], 0, 0, 0);
        __builtin_amdgcn_s_setprio(0);

        // Counted retire: slice s+1 must be landed for the next phase.
        if (s < NS - 3) {
            asm volatile("s_waitcnt vmcnt(8)" ::: "memory");
        } else if (s == NS - 3) {
            asm volatile("s_waitcnt vmcnt(4)" ::: "memory");
        } else if (s == NS - 2) {
            asm volatile("s_waitcnt vmcnt(0)" ::: "memory");
        }
        if (s < NS - 1) {
            __builtin_amdgcn_sched_barrier(0);
            __builtin_amdgcn_s_barrier();
        }
    }
    #undef STAGE

    // Epilogue: C/D layout col=lane&15, row=(lane>>4)*4+reg. Apply per-expert scale.
    const float sc = scale[e];
    float* Cbase = out + ((size_t)e * T_ + m0 + wr * 128) * DO_ + n0 + wc * 64;
    #pragma unroll
    for (int i = 0; i < 8; i++) {
        #pragma unroll
        for (int j = 0; j < 4; j++) {
            #pragma unroll
            for (int r = 0; r < 4; r++) {
                const int row = i * 16 + fq * 4 + r;
                const int col = j * 16 + fr;
                Cbase[(size_t)row * DO_ + col] = acc[i][j][r] * sc;
            }
        }
    }
}

// ---------------------------------------------------------------------------
// Fallback: fused kernel (used only if workspace is too small).
// ---------------------------------------------------------------------------
#define FBM  128
#define FBN  128
#define FBK  64
#define FPAD 8
#define FLDST (FBK + FPAD)

__global__ __launch_bounds__(256, 2)
void qgemm_bf16_kernel(const float* __restrict__ input,
                       const int*   __restrict__ weight,
                       const float* __restrict__ scale,
                       float*       __restrict__ out) {
    __shared__ ushort As[FBM * FLDST];
    __shared__ ushort Bs[FBN * FLDST];

    const int tid = threadIdx.x;
    const int e   = blockIdx.y;
    const int m0 = (blockIdx.x & 7) * FBM;
    const int n0 = (blockIdx.x >> 3) * FBN;

    const float* Abase = input  + ((size_t)e * T_  + m0) * DI_;
    const int*   Bbase = weight + ((size_t)e * DO_ + n0) * DI_;

    const int srow = tid >> 3;
    const int scol = (tid & 7) * 8;

    const int lane = tid & 63;
    const int wave = tid >> 6;
    const int wm = (wave >> 1) * 64;
    const int wn = (wave & 1) * 64;
    const int fr = lane & 15;
    const int fq = lane >> 4;

    f32x4 acc[4][4];
    #pragma unroll
    for (int i = 0; i < 4; i++)
        #pragma unroll
        for (int j = 0; j < 4; j++)
            acc[i][j] = (f32x4){0.f, 0.f, 0.f, 0.f};

    float4 aRegs[4][2];
    int4   bRegs[4][2];

    #pragma unroll
    for (int p = 0; p < 4; p++) {
        const float* ap = Abase + (size_t)(srow + p * 32) * DI_ + scol;
        aRegs[p][0] = *(const float4*)ap;
        aRegs[p][1] = *(const float4*)(ap + 4);
        const int* bp = Bbase + (size_t)(srow + p * 32) * DI_ + scol;
        bRegs[p][0] = *(const int4*)bp;
        bRegs[p][1] = *(const int4*)(bp + 4);
    }

    const int KT = DI_ / FBK;
    for (int kt = 0; kt < KT; kt++) {
        #pragma unroll
        for (int p = 0; p < 4; p++) {
            float4 f0 = aRegs[p][0], f1 = aRegs[p][1];
            uint4 w;
            w.x = pack_bf16(__float_as_uint(f0.x), __float_as_uint(f0.y));
            w.y = pack_bf16(__float_as_uint(f0.z), __float_as_uint(f0.w));
            w.z = pack_bf16(__float_as_uint(f1.x), __float_as_uint(f1.y));
            w.w = pack_bf16(__float_as_uint(f1.z), __float_as_uint(f1.w));
            *(uint4*)&As[(srow + p * 32) * FLDST + scol] = w;

            int4 i0 = bRegs[p][0], i1 = bRegs[p][1];
            uint4 v;
            v.x = pack_bf16(__float_as_uint((float)i0.x), __float_as_uint((float)i0.y));
            v.y = pack_bf16(__float_as_uint((float)i0.z), __float_as_uint((float)i0.w));
            v.z = pack_bf16(__float_as_uint((float)i1.x), __float_as_uint((float)i1.y));
            v.w = pack_bf16(__float_as_uint((float)i1.z), __float_as_uint((float)i1.w));
            *(uint4*)&Bs[(srow + p * 32) * FLDST + scol] = v;
        }
        __syncthreads();

        if (kt + 1 < KT) {
            const float* An = Abase + (size_t)(kt + 1) * FBK;
            const int*   Bn = Bbase + (size_t)(kt + 1) * FBK;
            #pragma unroll
            for (int p = 0; p < 4; p++) {
                const float* ap = An + (size_t)(srow + p * 32) * DI_ + scol;
                aRegs[p][0] = *(const float4*)ap;
                aRegs[p][1] = *(const float4*)(ap + 4);
                const int* bp = Bn + (size_t)(srow + p * 32) * DI_ + scol;
                bRegs[p][0] = *(const int4*)bp;
                bRegs[p][1] = *(const int4*)(bp + 4);
            }
        }

        #pragma unroll
        for (int ks = 0; ks < 2; ks++) {
            bf16x8 afrag[4], bfrag[4];
            #pragma unroll
            for (int i = 0; i < 4; i++) {
                afrag[i] = *(const bf16x8*)&As[(wm + i * 16 + fr) * FLDST + ks * 32 + fq * 8];
                bfrag[i] = *(const bf16x8*)&Bs[(wn + i * 16 + fr) * FLDST + ks * 32 + fq * 8];
            }
            #pragma unroll
            for (int i = 0; i < 4; i++)
                #pragma unroll
                for (int j = 0; j < 4; j++)
                    acc[i][j] = __builtin_amdgcn_mfma_f32_16x16x32_bf16(
                        afrag[i], bfrag[j], acc[i][j], 0, 0, 0);
        }
        __syncthreads();
    }

    const float s = scale[e];
    float* Cbase = out + ((size_t)e * T_ + m0) * DO_ + n0;
    #pragma unroll
    for (int i = 0; i < 4; i++) {
        #pragma unroll
        for (int j = 0; j < 4; j++) {
            #pragma unroll
            for (int r = 0; r < 4; r++) {
                const int row = wm + i * 16 + fq * 4 + r;
                const int col = wn + j * 16 + fr;
                Cbase[(size_t)row * DO_ + col] = acc[i][j][r] * s;
            }
        }
    }
}

// ---------------------------------------------------------------------------
extern "C" void kernel_launch(void* const* d_in, const int* in_sizes, int n_in,
                              void* d_out, int out_size, void* d_ws, size_t ws_size,
                              hipStream_t stream) {
    const float* input  = (const float*)d_in[0];
    const int*   weight = (const int*)d_in[1];
    const float* scale  = (const float*)d_in[2];
    float* out = (float*)d_out;

    const size_t wbytes = (size_t)E_ * DO_ * DI_ * sizeof(ushort);  // 256 MiB
    const size_t abytes = (size_t)E_ * T_  * DI_ * sizeof(ushort);  //  32 MiB

    if (d_ws != nullptr && ws_size >= wbytes + abytes) {
        ushort* Wbf = (ushort*)d_ws;
        ushort* Abf = (ushort*)((char*)d_ws + wbytes);
        cvt_w_kernel<<<dim3(2048), dim3(256), 0, stream>>>(weight, Wbf);
        cvt_a_kernel<<<dim3(1024), dim3(256), 0, stream>>>(input, Abf);
        const int nblocks = (T_ / BM) * (DO_ / BN) * E_;  // 4*32*8 = 1024
        qgemm_ring_kernel<<<dim3(nblocks), dim3(512), 0, stream>>>(Abf, Wbf, scale, out);
    } else {
        dim3 grid((T_ / FBM) * (DO_ / FBN), E_, 1);
        qgemm_bf16_kernel<<<grid, dim3(256), 0, stream>>>(input, weight, scale, out);
    }
}